// Round 1
// baseline (92.713 us; speedup 1.0000x reference)
//
#include <hip/hip_runtime.h>
#include <math.h>

// Problem constants (B=1)
#define HH   96
#define WW   96
#define NPIX 9216          // H*W = number of pixels = number of gaussians
#define TWT  6             // (96+15)/16
#define THT  6

__device__ __forceinline__ float sigmoidf_(float x) {
    return 1.0f / (1.0f + __expf(-x));
}

// Kernel 1: fused (3x3 conv 3->64) + (1x1 head 64->8) via folded weights,
// then per-gaussian derived parameters, written SoA to workspace.
// gp layout: [0]=cx [1]=cy [2]=ca [3]=cb [4]=cc [5]=r [6]=g [7]=b, each NPIX floats.
// gb: packed tile bounds per gaussian: tminx | tmaxx<<8 | tminy<<16 | tmaxy<<24.
__global__ __launch_bounds__(256) void gauss_params_kernel(
    const float* __restrict__ inp, const float* __restrict__ w_enc,
    const float* __restrict__ b_enc, const float* __restrict__ w_head,
    const float* __restrict__ b_head, float* __restrict__ gp, int* __restrict__ gb)
{
    __shared__ float wcomb[8][27];   // folded conv weights: [o][i*9+ky*3+kx]
    __shared__ float bcomb[8];
    const int tid = threadIdx.x;

    // Fold head into conv weights (redundant per block; 64 MACs/thread — trivial).
    if (tid < 216) {
        const int o = tid / 27, r = tid % 27;
        float acc = 0.0f;
        for (int c = 0; c < 64; ++c)
            acc = fmaf(w_head[o * 64 + c], w_enc[c * 27 + r], acc);
        wcomb[o][r] = acc;
    } else if (tid < 224) {
        const int o = tid - 216;
        float acc = b_head[o];
        for (int c = 0; c < 64; ++c)
            acc = fmaf(w_head[o * 64 + c], b_enc[c], acc);
        bcomb[o] = acc;
    }
    __syncthreads();

    const int p   = blockIdx.x * 256 + tid;   // grid is exactly 36 blocks
    const int row = p / WW, col = p % WW;

    // 3x3x3 zero-padded input patch
    float patch[27];
    #pragma unroll
    for (int i = 0; i < 3; ++i) {
        #pragma unroll
        for (int dy = 0; dy < 3; ++dy) {
            const int y = row + dy - 1;
            #pragma unroll
            for (int dx = 0; dx < 3; ++dx) {
                const int x = col + dx - 1;
                float v = 0.0f;
                if (y >= 0 && y < HH && x >= 0 && x < WW)
                    v = inp[i * NPIX + y * WW + x];
                patch[(i * 3 + dy) * 3 + dx] = v;
            }
        }
    }

    float pred[8];
    #pragma unroll
    for (int o = 0; o < 8; ++o) {
        float acc = bcomb[o];
        #pragma unroll
        for (int r = 0; r < 27; ++r)
            acc = fmaf(wcomb[o][r], patch[r], acc);
        pred[o] = acc;
    }

    // Derived gaussian parameters (exactly following the reference formulas)
    const float theta = sigmoidf_(pred[3]) * 6.28318530717958647692f;
    const float cth = cosf(theta), sth = sinf(theta);
    const float s0 = sigmoidf_(pred[4]) * 0.5f + 1e-6f;
    const float s1 = sigmoidf_(pred[5]) * 0.5f + 1e-6f;
    const float v0 = s0 * s0, v1 = s1 * s1;
    const float S00 = cth * cth * v0 + sth * sth * v1;
    const float S01 = cth * sth * (v0 - v1);
    const float S11 = sth * sth * v0 + cth * cth * v1;
    const float det = S00 * S11 - S01 * S01;
    const float inv_det = 1.0f / det;
    const float ca = S11 * inv_det;
    const float cb = -S01 * inv_det;
    const float cc = S00 * inv_det;
    const float bmid = 0.5f * (S00 + S11);
    const float lam1 = bmid + sqrtf(fmaxf(0.1f, bmid * bmid - det));
    const float radius = ceilf(3.0f * sqrtf(lam1));   // always 2 or 3 (see analysis)
    const float off0 = tanhf(pred[6]);
    const float off1 = tanhf(pred[7]);
    const float coord0 = 2.0f * (float)col / (float)WW - 1.0f;
    const float coord1 = 2.0f * (float)row / (float)HH - 1.0f;
    const float x_ndc = coord0 + 2.0f * off0 / (float)WW - 1.0f / (float)WW;
    const float y_ndc = coord1 + 2.0f * off1 / (float)HH - 1.0f / (float)HH;
    const float cx = 0.5f * (float)WW * (x_ndc + 1.0f) - 0.5f;
    const float cy = 0.5f * (float)HH * (y_ndc + 1.0f) - 0.5f;

    // Tile bounds, trunc-toward-zero cast then clip — matches .astype(int32)+clip
    int tminx = (int)((cx - radius) / 16.0f);
    int tmaxx = (int)((cx + radius) / 16.0f) + 1;
    int tminy = (int)((cy - radius) / 16.0f);
    int tmaxy = (int)((cy + radius) / 16.0f) + 1;
    tminx = min(max(tminx, 0), TWT); tmaxx = min(max(tmaxx, 0), TWT);
    tminy = min(max(tminy, 0), THT); tmaxy = min(max(tmaxy, 0), THT);
    if (!(radius > 0.0f)) { tmaxx = tminx; tmaxy = tminy; }  // radius<=0 or NaN -> empty

    gp[0 * NPIX + p] = cx;
    gp[1 * NPIX + p] = cy;
    gp[2 * NPIX + p] = ca;
    gp[3 * NPIX + p] = cb;
    gp[4 * NPIX + p] = cc;
    gp[5 * NPIX + p] = pred[0];
    gp[6 * NPIX + p] = pred[1];
    gp[7 * NPIX + p] = pred[2];
    gb[p] = tminx | (tmaxx << 8) | (tminy << 16) | (tmaxy << 24);
}

// Kernel 2: per-pixel gather over the provably-sufficient 9x9 source window.
// Bound: |gaussian center - pixel| <= 2.04 px and center in (src_col-2, src_col),
// so contributing sources satisfy col_n in [col_p-2, col_p+4]; we use [-3,+5].
__global__ __launch_bounds__(256) void rasterize_kernel(
    const float* __restrict__ gp, const int* __restrict__ gb,
    float* __restrict__ out)
{
    const int p   = blockIdx.x * 256 + threadIdx.x;
    const int row = p / WW, col = p % WW;
    const int tx = col >> 4, ty = row >> 4;
    const float px = (float)col, py = (float)row;

    const int gr0 = max(row - 3, 0), gr1 = min(row + 5, HH - 1);
    const int gc0 = max(col - 3, 0), gc1 = min(col + 5, WW - 1);

    float aR = 0.0f, aG = 0.0f, aB = 0.0f;
    for (int gr = gr0; gr <= gr1; ++gr) {
        for (int gc = gc0; gc <= gc1; ++gc) {
            const int n = gr * WW + gc;
            const float dx = gp[0 * NPIX + n] - px;
            const float dy = gp[1 * NPIX + n] - py;
            const float ca = gp[2 * NPIX + n];
            const float cb = gp[3 * NPIX + n];
            const float cc = gp[4 * NPIX + n];
            const float sigma = 0.5f * (ca * dx * dx + cc * dy * dy) + cb * dx * dy;
            const float alpha = fminf(0.999f, __expf(-sigma));
            const int bnd = gb[n];
            // NaN sigma -> (sigma>=0) false -> invalid (matches numpy semantics)
            const bool valid = (sigma >= 0.0f) && (alpha >= (1.0f / 255.0f)) &&
                               (tx >= (bnd & 0xff)) && (tx < ((bnd >> 8) & 0xff)) &&
                               (ty >= ((bnd >> 16) & 0xff)) && (ty < ((bnd >> 24) & 0xff));
            if (valid) {
                aR = fmaf(alpha, gp[5 * NPIX + n], aR);
                aG = fmaf(alpha, gp[6 * NPIX + n], aG);
                aB = fmaf(alpha, gp[7 * NPIX + n], aB);
            }
        }
    }
    out[0 * NPIX + p] = fminf(fmaxf(aR, 0.0f), 1.0f);
    out[1 * NPIX + p] = fminf(fmaxf(aG, 0.0f), 1.0f);
    out[2 * NPIX + p] = fminf(fmaxf(aB, 0.0f), 1.0f);
}

extern "C" void kernel_launch(void* const* d_in, const int* in_sizes, int n_in,
                              void* d_out, int out_size, void* d_ws, size_t ws_size,
                              hipStream_t stream)
{
    const float* inp    = (const float*)d_in[0];  // (1,3,96,96)
    const float* w_enc  = (const float*)d_in[1];  // (64,3,3,3)
    const float* b_enc  = (const float*)d_in[2];  // (64,)
    const float* w_head = (const float*)d_in[3];  // (8,64)
    const float* b_head = (const float*)d_in[4];  // (8,)
    float* out = (float*)d_out;                   // (1,3,96,96)

    float* gp = (float*)d_ws;                     // 8*NPIX floats
    int*   gb = (int*)((float*)d_ws + 8 * NPIX);  // NPIX ints  (total ~332 KB)

    gauss_params_kernel<<<36, 256, 0, stream>>>(inp, w_enc, b_enc, w_head, b_head, gp, gb);
    rasterize_kernel<<<36, 256, 0, stream>>>(gp, gb, out);
}

// Round 2
// 75.363 us; speedup vs baseline: 1.2302x; 1.2302x over previous
//
#include <hip/hip_runtime.h>
#include <math.h>

// Problem constants (B=1)
#define HH   96
#define WW   96
#define NPIX 9216          // H*W = number of pixels = number of gaussians
#define TWT  6             // (96+15)/16
#define THT  6

__device__ __forceinline__ float sigmoidf_(float x) {
    return 1.0f / (1.0f + __expf(-x));
}

// Kernel 1: fused (3x3 conv 3->64) + (1x1 head 64->8) via folded weights,
// then per-gaussian derived parameters, written SoA to workspace.
// gp layout: [0]=cx [1]=cy [2]=ca [3]=cb [4]=cc [5]=r [6]=g [7]=b, each NPIX floats.
// gb: packed tile bounds per gaussian: tminx | tmaxx<<8 | tminy<<16 | tmaxy<<24.
__global__ __launch_bounds__(256) void gauss_params_kernel(
    const float* __restrict__ inp, const float* __restrict__ w_enc,
    const float* __restrict__ b_enc, const float* __restrict__ w_head,
    const float* __restrict__ b_head, float* __restrict__ gp, int* __restrict__ gb)
{
    __shared__ float wcomb[8][27];   // folded conv weights: [o][i*9+ky*3+kx]
    __shared__ float bcomb[8];
    const int tid = threadIdx.x;

    // Fold head into conv weights (redundant per block; 64 MACs/thread — trivial).
    if (tid < 216) {
        const int o = tid / 27, r = tid % 27;
        float acc = 0.0f;
        for (int c = 0; c < 64; ++c)
            acc = fmaf(w_head[o * 64 + c], w_enc[c * 27 + r], acc);
        wcomb[o][r] = acc;
    } else if (tid < 224) {
        const int o = tid - 216;
        float acc = b_head[o];
        for (int c = 0; c < 64; ++c)
            acc = fmaf(w_head[o * 64 + c], b_enc[c], acc);
        bcomb[o] = acc;
    }
    __syncthreads();

    const int p   = blockIdx.x * 256 + tid;   // grid is exactly 36 blocks
    const int row = p / WW, col = p % WW;

    // 3x3x3 zero-padded input patch
    float patch[27];
    #pragma unroll
    for (int i = 0; i < 3; ++i) {
        #pragma unroll
        for (int dy = 0; dy < 3; ++dy) {
            const int y = row + dy - 1;
            #pragma unroll
            for (int dx = 0; dx < 3; ++dx) {
                const int x = col + dx - 1;
                float v = 0.0f;
                if (y >= 0 && y < HH && x >= 0 && x < WW)
                    v = inp[i * NPIX + y * WW + x];
                patch[(i * 3 + dy) * 3 + dx] = v;
            }
        }
    }

    float pred[8];
    #pragma unroll
    for (int o = 0; o < 8; ++o) {
        float acc = bcomb[o];
        #pragma unroll
        for (int r = 0; r < 27; ++r)
            acc = fmaf(wcomb[o][r], patch[r], acc);
        pred[o] = acc;
    }

    // Derived gaussian parameters (exactly following the reference formulas)
    const float theta = sigmoidf_(pred[3]) * 6.28318530717958647692f;
    const float cth = cosf(theta), sth = sinf(theta);
    const float s0 = sigmoidf_(pred[4]) * 0.5f + 1e-6f;
    const float s1 = sigmoidf_(pred[5]) * 0.5f + 1e-6f;
    const float v0 = s0 * s0, v1 = s1 * s1;
    const float S00 = cth * cth * v0 + sth * sth * v1;
    const float S01 = cth * sth * (v0 - v1);
    const float S11 = sth * sth * v0 + cth * cth * v1;
    const float det = S00 * S11 - S01 * S01;
    const float inv_det = 1.0f / det;
    const float ca = S11 * inv_det;
    const float cb = -S01 * inv_det;
    const float cc = S00 * inv_det;
    const float bmid = 0.5f * (S00 + S11);
    const float lam1 = bmid + sqrtf(fmaxf(0.1f, bmid * bmid - det));
    const float radius = ceilf(3.0f * sqrtf(lam1));   // always 2 or 3 (see analysis)
    const float off0 = tanhf(pred[6]);
    const float off1 = tanhf(pred[7]);
    const float coord0 = 2.0f * (float)col / (float)WW - 1.0f;
    const float coord1 = 2.0f * (float)row / (float)HH - 1.0f;
    const float x_ndc = coord0 + 2.0f * off0 / (float)WW - 1.0f / (float)WW;
    const float y_ndc = coord1 + 2.0f * off1 / (float)HH - 1.0f / (float)HH;
    const float cx = 0.5f * (float)WW * (x_ndc + 1.0f) - 0.5f;
    const float cy = 0.5f * (float)HH * (y_ndc + 1.0f) - 0.5f;

    // Tile bounds, trunc-toward-zero cast then clip — matches .astype(int32)+clip
    int tminx = (int)((cx - radius) / 16.0f);
    int tmaxx = (int)((cx + radius) / 16.0f) + 1;
    int tminy = (int)((cy - radius) / 16.0f);
    int tmaxy = (int)((cy + radius) / 16.0f) + 1;
    tminx = min(max(tminx, 0), TWT); tmaxx = min(max(tmaxx, 0), TWT);
    tminy = min(max(tminy, 0), THT); tmaxy = min(max(tmaxy, 0), THT);
    if (!(radius > 0.0f)) { tmaxx = tminx; tmaxy = tminy; }  // radius<=0 or NaN -> empty

    gp[0 * NPIX + p] = cx;
    gp[1 * NPIX + p] = cy;
    gp[2 * NPIX + p] = ca;
    gp[3 * NPIX + p] = cb;
    gp[4 * NPIX + p] = cc;
    gp[5 * NPIX + p] = pred[0];
    gp[6 * NPIX + p] = pred[1];
    gp[7 * NPIX + p] = pred[2];
    gb[p] = tminx | (tmaxx << 8) | (tminy << 16) | (tmaxy << 24);
}

// Kernel 2: per-pixel gather over the provably-sufficient 9x9 source window,
// split 8 lanes per pixel for TLP (81 candidates -> ~10-11 per lane), then
// an 8-lane butterfly reduction. Grid: 288 blocks x 256 = 1152 waves (full chip).
__global__ __launch_bounds__(256) void rasterize_kernel(
    const float* __restrict__ gp, const int* __restrict__ gb,
    float* __restrict__ out)
{
    const int t     = blockIdx.x * 256 + threadIdx.x;
    const int p     = t >> 3;        // pixel index
    const int slice = t & 7;         // candidate slice within the 9x9 window
    const int row = p / WW, col = p % WW;
    const int tx = col >> 4, ty = row >> 4;
    const float px = (float)col, py = (float)row;

    float aR = 0.0f, aG = 0.0f, aB = 0.0f;
    for (int idx = slice; idx < 81; idx += 8) {
        const int wr = idx / 9, wc = idx - wr * 9;
        const int gr = row - 3 + wr;
        const int gc = col - 3 + wc;
        if (gr < 0 || gr >= HH || gc < 0 || gc >= WW) continue;
        const int n = gr * WW + gc;
        const float dx = gp[0 * NPIX + n] - px;
        const float dy = gp[1 * NPIX + n] - py;
        const float ca = gp[2 * NPIX + n];
        const float cb = gp[3 * NPIX + n];
        const float cc = gp[4 * NPIX + n];
        const float sigma = 0.5f * (ca * dx * dx + cc * dy * dy) + cb * dx * dy;
        const float alpha = fminf(0.999f, __expf(-sigma));
        const int bnd = gb[n];
        // NaN sigma -> (sigma>=0) false -> invalid (matches numpy semantics)
        const bool valid = (sigma >= 0.0f) && (alpha >= (1.0f / 255.0f)) &&
                           (tx >= (bnd & 0xff)) && (tx < ((bnd >> 8) & 0xff)) &&
                           (ty >= ((bnd >> 16) & 0xff)) && (ty < ((bnd >> 24) & 0xff));
        if (valid) {
            aR = fmaf(alpha, gp[5 * NPIX + n], aR);
            aG = fmaf(alpha, gp[6 * NPIX + n], aG);
            aB = fmaf(alpha, gp[7 * NPIX + n], aB);
        }
    }

    // 8-lane butterfly: lanes (t & ~7)..(t|7) share a pixel; masks 1/2/4 stay inside.
    aR += __shfl_xor(aR, 1); aR += __shfl_xor(aR, 2); aR += __shfl_xor(aR, 4);
    aG += __shfl_xor(aG, 1); aG += __shfl_xor(aG, 2); aG += __shfl_xor(aG, 4);
    aB += __shfl_xor(aB, 1); aB += __shfl_xor(aB, 2); aB += __shfl_xor(aB, 4);

    // After the butterfly all 8 lanes hold the full sums; lanes 0..2 write ch 0..2.
    if (slice < 3) {
        const float v = (slice == 0) ? aR : (slice == 1) ? aG : aB;
        out[slice * NPIX + p] = fminf(fmaxf(v, 0.0f), 1.0f);
    }
}

extern "C" void kernel_launch(void* const* d_in, const int* in_sizes, int n_in,
                              void* d_out, int out_size, void* d_ws, size_t ws_size,
                              hipStream_t stream)
{
    const float* inp    = (const float*)d_in[0];  // (1,3,96,96)
    const float* w_enc  = (const float*)d_in[1];  // (64,3,3,3)
    const float* b_enc  = (const float*)d_in[2];  // (64,)
    const float* w_head = (const float*)d_in[3];  // (8,64)
    const float* b_head = (const float*)d_in[4];  // (8,)
    float* out = (float*)d_out;                   // (1,3,96,96)

    float* gp = (float*)d_ws;                     // 8*NPIX floats
    int*   gb = (int*)((float*)d_ws + 8 * NPIX);  // NPIX ints  (total ~332 KB)

    gauss_params_kernel<<<36, 256, 0, stream>>>(inp, w_enc, b_enc, w_head, b_head, gp, gb);
    rasterize_kernel<<<(NPIX * 8) / 256, 256, 0, stream>>>(gp, gb, out);
}

// Round 3
// 72.791 us; speedup vs baseline: 1.2737x; 1.0353x over previous
//
#include <hip/hip_runtime.h>
#include <math.h>

// Problem constants (B=1)
#define HH   96
#define WW   96
#define NPIX 9216          // H*W = number of pixels = number of gaussians
#define TWT  6             // (96+15)/16
#define THT  6

__device__ __forceinline__ float fast_sigmoid(float x) {
    return 1.0f / (1.0f + __expf(-x));
}
// tanh via exp: exact at saturation, ~1e-7 rel error mid-range.
__device__ __forceinline__ float fast_tanh(float x) {
    return 1.0f - 2.0f / (__expf(2.0f * x) + 1.0f);
}

// Workspace layout (AoS float4 pairs so rasterize does 2x dwordx4 + 1 dword per cand):
//   gpA[n] = (cx, cy, ca, cb)
//   gpB[n] = (cc, r, g, b)
//   gb[n]  = packed tile bounds: tminx | tmaxx<<8 | tminy<<16 | tmaxy<<24

// Kernel 1: fused (3x3 conv 3->64) + (1x1 head 64->8) via folded weights,
// then per-gaussian derived parameters.
__global__ __launch_bounds__(256) void gauss_params_kernel(
    const float* __restrict__ inp, const float* __restrict__ w_enc,
    const float* __restrict__ b_enc, const float* __restrict__ w_head,
    const float* __restrict__ b_head,
    float4* __restrict__ gpA, float4* __restrict__ gpB, int* __restrict__ gb)
{
    __shared__ float wcomb[8][27];   // folded conv weights: [o][i*9+ky*3+kx]
    __shared__ float bcomb[8];
    const int tid = threadIdx.x;

    // Fold head into conv weights (redundant per block; trivial).
    if (tid < 216) {
        const int o = tid / 27, r = tid % 27;
        float acc = 0.0f;
        for (int c = 0; c < 64; ++c)
            acc = fmaf(w_head[o * 64 + c], w_enc[c * 27 + r], acc);
        wcomb[o][r] = acc;
    } else if (tid < 224) {
        const int o = tid - 216;
        float acc = b_head[o];
        for (int c = 0; c < 64; ++c)
            acc = fmaf(w_head[o * 64 + c], b_enc[c], acc);
        bcomb[o] = acc;
    }
    __syncthreads();

    const int p   = blockIdx.x * 256 + tid;   // grid is exactly 36 blocks
    const int row = p / WW, col = p % WW;

    // 3x3x3 zero-padded input patch
    float patch[27];
    #pragma unroll
    for (int i = 0; i < 3; ++i) {
        #pragma unroll
        for (int dy = 0; dy < 3; ++dy) {
            const int y = row + dy - 1;
            #pragma unroll
            for (int dx = 0; dx < 3; ++dx) {
                const int x = col + dx - 1;
                float v = 0.0f;
                if (y >= 0 && y < HH && x >= 0 && x < WW)
                    v = inp[i * NPIX + y * WW + x];
                patch[(i * 3 + dy) * 3 + dx] = v;
            }
        }
    }

    float pred[8];
    #pragma unroll
    for (int o = 0; o < 8; ++o) {
        float acc = bcomb[o];
        #pragma unroll
        for (int r = 0; r < 27; ++r)
            acc = fmaf(wcomb[o][r], patch[r], acc);
        pred[o] = acc;
    }

    // Derived gaussian parameters (reference formulas; fast transcendentals —
    // theta in [0,2pi] is inside v_sin/v_cos accurate range).
    const float theta = fast_sigmoid(pred[3]) * 6.28318530717958647692f;
    const float cth = __cosf(theta), sth = __sinf(theta);
    const float s0 = fast_sigmoid(pred[4]) * 0.5f + 1e-6f;
    const float s1 = fast_sigmoid(pred[5]) * 0.5f + 1e-6f;
    const float v0 = s0 * s0, v1 = s1 * s1;
    const float S00 = cth * cth * v0 + sth * sth * v1;
    const float S01 = cth * sth * (v0 - v1);
    const float S11 = sth * sth * v0 + cth * cth * v1;
    const float det = S00 * S11 - S01 * S01;
    const float inv_det = 1.0f / det;
    const float ca = S11 * inv_det;
    const float cb = -S01 * inv_det;
    const float cc = S00 * inv_det;
    const float bmid = 0.5f * (S00 + S11);
    const float lam1 = bmid + sqrtf(fmaxf(0.1f, bmid * bmid - det));
    const float radius = ceilf(3.0f * sqrtf(lam1));   // always 2 or 3 (see analysis)
    const float off0 = fast_tanh(pred[6]);
    const float off1 = fast_tanh(pred[7]);
    const float coord0 = 2.0f * (float)col / (float)WW - 1.0f;
    const float coord1 = 2.0f * (float)row / (float)HH - 1.0f;
    const float x_ndc = coord0 + 2.0f * off0 / (float)WW - 1.0f / (float)WW;
    const float y_ndc = coord1 + 2.0f * off1 / (float)HH - 1.0f / (float)HH;
    const float cx = 0.5f * (float)WW * (x_ndc + 1.0f) - 0.5f;
    const float cy = 0.5f * (float)HH * (y_ndc + 1.0f) - 0.5f;

    // Tile bounds, trunc-toward-zero cast then clip — matches .astype(int32)+clip
    int tminx = (int)((cx - radius) / 16.0f);
    int tmaxx = (int)((cx + radius) / 16.0f) + 1;
    int tminy = (int)((cy - radius) / 16.0f);
    int tmaxy = (int)((cy + radius) / 16.0f) + 1;
    tminx = min(max(tminx, 0), TWT); tmaxx = min(max(tmaxx, 0), TWT);
    tminy = min(max(tminy, 0), THT); tmaxy = min(max(tmaxy, 0), THT);
    if (!(radius > 0.0f)) { tmaxx = tminx; tmaxy = tminy; }  // radius<=0 or NaN -> empty

    gpA[p] = make_float4(cx, cy, ca, cb);
    gpB[p] = make_float4(cc, pred[0], pred[1], pred[2]);
    gb[p]  = tminx | (tmaxx << 8) | (tminy << 16) | (tmaxy << 24);
}

// Kernel 2: per-pixel gather over the provably-sufficient 9x9 source window,
// split 8 lanes per pixel for TLP, 8-lane butterfly reduction.
// Grid: 288 blocks x 256 = 1152 waves (full chip).
__global__ __launch_bounds__(256) void rasterize_kernel(
    const float4* __restrict__ gpA, const float4* __restrict__ gpB,
    const int* __restrict__ gb, float* __restrict__ out)
{
    const int t     = blockIdx.x * 256 + threadIdx.x;
    const int p     = t >> 3;        // pixel index
    const int slice = t & 7;         // candidate slice within the 9x9 window
    const int row = p / WW, col = p % WW;
    const int tx = col >> 4, ty = row >> 4;
    const float px = (float)col, py = (float)row;

    float aR = 0.0f, aG = 0.0f, aB = 0.0f;
    for (int idx = slice; idx < 81; idx += 8) {
        const int wr = idx / 9, wc = idx - wr * 9;
        const int gr = row - 3 + wr;
        const int gc = col - 3 + wc;
        if (gr < 0 || gr >= HH || gc < 0 || gc >= WW) continue;
        const int n = gr * WW + gc;
        const float4 A  = gpA[n];
        const float4 Bv = gpB[n];
        const float dx = A.x - px;
        const float dy = A.y - py;
        const float sigma = 0.5f * (A.z * dx * dx + Bv.x * dy * dy) + A.w * dx * dy;
        const float alpha = fminf(0.999f, __expf(-sigma));
        const int bnd = gb[n];
        // NaN sigma -> (sigma>=0) false -> invalid (matches numpy semantics)
        const bool valid = (sigma >= 0.0f) && (alpha >= (1.0f / 255.0f)) &&
                           (tx >= (bnd & 0xff)) && (tx < ((bnd >> 8) & 0xff)) &&
                           (ty >= ((bnd >> 16) & 0xff)) && (ty < ((bnd >> 24) & 0xff));
        if (valid) {
            aR = fmaf(alpha, Bv.y, aR);
            aG = fmaf(alpha, Bv.z, aG);
            aB = fmaf(alpha, Bv.w, aB);
        }
    }

    // 8-lane butterfly: lanes (t & ~7)..(t|7) share a pixel; masks 1/2/4 stay inside.
    aR += __shfl_xor(aR, 1); aR += __shfl_xor(aR, 2); aR += __shfl_xor(aR, 4);
    aG += __shfl_xor(aG, 1); aG += __shfl_xor(aG, 2); aG += __shfl_xor(aG, 4);
    aB += __shfl_xor(aB, 1); aB += __shfl_xor(aB, 2); aB += __shfl_xor(aB, 4);

    if (slice < 3) {
        const float v = (slice == 0) ? aR : (slice == 1) ? aG : aB;
        out[slice * NPIX + p] = fminf(fmaxf(v, 0.0f), 1.0f);
    }
}

extern "C" void kernel_launch(void* const* d_in, const int* in_sizes, int n_in,
                              void* d_out, int out_size, void* d_ws, size_t ws_size,
                              hipStream_t stream)
{
    const float* inp    = (const float*)d_in[0];  // (1,3,96,96)
    const float* w_enc  = (const float*)d_in[1];  // (64,3,3,3)
    const float* b_enc  = (const float*)d_in[2];  // (64,)
    const float* w_head = (const float*)d_in[3];  // (8,64)
    const float* b_head = (const float*)d_in[4];  // (8,)
    float* out = (float*)d_out;                   // (1,3,96,96)

    float4* gpA = (float4*)d_ws;                  // NPIX float4
    float4* gpB = gpA + NPIX;                     // NPIX float4
    int*    gb  = (int*)(gpB + NPIX);             // NPIX ints  (total ~332 KB)

    gauss_params_kernel<<<36, 256, 0, stream>>>(inp, w_enc, b_enc, w_head, b_head, gpA, gpB, gb);
    rasterize_kernel<<<(NPIX * 8) / 256, 256, 0, stream>>>(gpA, gpB, gb, out);
}